// Round 1
// baseline (411.595 us; speedup 1.0000x reference)
//
#include <hip/hip_runtime.h>

// Elementwise clamp to [-0.5, 0.5]: memory-bound streaming kernel.
// float4 vector loads/stores = 16 B/lane, one element-group per thread.
__global__ __launch_bounds__(256) void clip_kernel_f4(const float4* __restrict__ x,
                                                      float4* __restrict__ out,
                                                      int n4) {
    int i = blockIdx.x * blockDim.x + threadIdx.x;
    if (i < n4) {
        float4 v = x[i];
        v.x = fminf(fmaxf(v.x, -0.5f), 0.5f);
        v.y = fminf(fmaxf(v.y, -0.5f), 0.5f);
        v.z = fminf(fmaxf(v.z, -0.5f), 0.5f);
        v.w = fminf(fmaxf(v.w, -0.5f), 0.5f);
        out[i] = v;
    }
}

// Tail (n not divisible by 4) — defensive; N = 16*2*2097152 is divisible by 4.
__global__ void clip_kernel_tail(const float* __restrict__ x,
                                 float* __restrict__ out,
                                 int start, int n) {
    int i = start + blockIdx.x * blockDim.x + threadIdx.x;
    if (i < n) {
        out[i] = fminf(fmaxf(x[i], -0.5f), 0.5f);
    }
}

extern "C" void kernel_launch(void* const* d_in, const int* in_sizes, int n_in,
                              void* d_out, int out_size, void* d_ws, size_t ws_size,
                              hipStream_t stream) {
    const float* x = (const float*)d_in[0];
    float* out = (float*)d_out;
    int n = in_sizes[0];

    int n4 = n / 4;
    if (n4 > 0) {
        int threads = 256;
        int blocks = (n4 + threads - 1) / threads;
        clip_kernel_f4<<<blocks, threads, 0, stream>>>((const float4*)x, (float4*)out, n4);
    }
    int rem = n - n4 * 4;
    if (rem > 0) {
        clip_kernel_tail<<<1, 64, 0, stream>>>(x, out, n4 * 4, n);
    }
}